// Round 6
// baseline (327.164 us; speedup 1.0000x reference)
//
#include <hip/hip_runtime.h>
#include <hip/hip_bf16.h>
#include <math.h>

// Problem constants
constexpr int Bn  = 4;
constexpr int Ln  = 1024;
constexpr int Dn  = 768;
constexpr int Hn  = 12;
constexpr int NEn = 42;
constexpr int Mn  = 8;
constexpr int Pn  = NEn * (NEn - 1);   // 1722
constexpr int UPn = Pn / 2;            // 861 unique i<j pairs (symmetry!)
constexpr int OFFn = 1;
constexpr float EPSn = 1e-5f;
constexpr int CL = 32;                 // l-chunk for k_pairs
constexpr int CHUNKS = Ln / CL;        // 32
constexpr int UHALF = 431;             // ceil(861/2)
constexpr int LDSW = 40;               // LDS row stride (shorts): 80B rows, 16B aligned

constexpr int SOT_BLKS = (Ln / 32) * (Dn / 32) * Bn;   // 3072
constexpr int EA_BLKS  = Bn * Hn * NEn;                // 2016

typedef __attribute__((ext_vector_type(8))) short bf16x8;
typedef __attribute__((ext_vector_type(4))) float f32x4;

__device__ inline unsigned short f2bf(float v) {  // RNE fp32 -> bf16 bits
    unsigned u = __float_as_uint(v);
    u += 0x7fffu + ((u >> 16) & 1u);
    return (unsigned short)(u >> 16);
}

// unique-pair index u (0..860, i<j row-major) -> (i, j).  off(i) = i*NE - i(i+1)/2
__device__ inline void u2ij(int u, int& oi, int& oj) {
    int ii = (int)((83.0f - sqrtf((float)(6889 - 8 * u))) * 0.5f);
    ii = ii < 0 ? 0 : (ii > NEn - 2 ? NEn - 2 : ii);
    while (ii > 0 && u < ii * NEn - ii * (ii + 1) / 2) --ii;
    while (u >= (ii + 1) * NEn - (ii + 1) * (ii + 2) / 2) ++ii;
    oi = ii;
    oj = u - (ii * NEn - ii * (ii + 1) / 2) + ii + 1;
}

// ---------------------------------------------------------------------------
// K1: entity_embed (fp32). Launched LAST so output 0 is written from pristine
// inputs at the very end of every launch (round-4 passing configuration).
// ---------------------------------------------------------------------------
__global__ __launch_bounds__(256) void k_entity_embed(
    const float* __restrict__ so, const float* __restrict__ mask,
    const int* __restrict__ mpos, float* __restrict__ out)
{
    const int be = blockIdx.x;
    const int b = be / NEn, e = be % NEn;
    __shared__ int   s_idx[Mn];
    __shared__ float s_msk[Mn];
    if (threadIdx.x < Mn) {
        const int m = threadIdx.x;
        s_idx[m] = mpos[(b * NEn + e) * Mn + m] + OFFn;
        s_msk[m] = mask[(b * NEn + e) * Mn + m];
    }
    __syncthreads();
    for (int d = threadIdx.x; d < Dn; d += 256) {
        float v[Mn];
        float mx = -3.4e38f;
        #pragma unroll
        for (int m = 0; m < Mn; ++m) {
            const float val = so[((size_t)b * Ln + s_idx[m]) * Dn + d];
            v[m] = (s_msk[m] > 0.f) ? val : -3.4e38f;
            mx = fmaxf(mx, v[m]);
        }
        float s = 0.f;
        #pragma unroll
        for (int m = 0; m < Mn; ++m)
            s += (v[m] > -3.0e38f) ? __expf(v[m] - mx) : 0.f;
        out[((size_t)b * NEn + e) * Dn + d] = mx + __logf(s);
    }
}

// ---------------------------------------------------------------------------
// K_prep: fused  [blocks 0..SOT_BLKS)  : so -> soT (bf16, transposed)
//                [SOT_BLKS..+EA_BLKS)  : entity_att -> ea2 (bf16)
// ---------------------------------------------------------------------------
__global__ __launch_bounds__(256) void k_prep(
    const float* __restrict__ so, const float* __restrict__ att,
    const float* __restrict__ mask, const int* __restrict__ mpos,
    unsigned short* __restrict__ soT, unsigned short* __restrict__ ea2)
{
    const int bx = blockIdx.x;
    if (bx < SOT_BLKS) {
        __shared__ unsigned short tile[32][33];
        const int rem = bx % ((Ln / 32) * (Dn / 32));
        const int b   = bx / ((Ln / 32) * (Dn / 32));
        const int l0  = (rem % (Ln / 32)) * 32;
        const int d0  = (rem / (Ln / 32)) * 32;
        const int cx = threadIdx.x & 31;
        const int ry = threadIdx.x >> 5;  // 0..7
        for (int r = ry; r < 32; r += 8)
            tile[r][cx] = f2bf(so[((size_t)b * Ln + l0 + r) * Dn + d0 + cx]);
        __syncthreads();
        for (int r = ry; r < 32; r += 8)
            soT[((size_t)b * Dn + d0 + r) * Ln + l0 + cx] = tile[cx][r];
    } else {
        const int id = bx - SOT_BLKS;     // ((b*H)+h)*NE + e
        const int e = id % NEn;
        const int bh = id / NEn;
        const int h = bh % Hn;
        const int b = bh / Hn;
        __shared__ int   s_idx[Mn];
        __shared__ float s_w[Mn];
        __shared__ float s_inv;
        if (threadIdx.x == 0) {
            float sum = 0.f;
            for (int m = 0; m < Mn; ++m) {
                s_idx[m] = mpos[(b * NEn + e) * Mn + m] + OFFn;
                const float w = mask[(b * NEn + e) * Mn + m];
                s_w[m] = w; sum += w;
            }
            s_inv = 1.f / sum;
        }
        __syncthreads();
        const int l = threadIdx.x * 4;
        float4 acc = {0.f, 0.f, 0.f, 0.f};
        #pragma unroll
        for (int m = 0; m < Mn; ++m) {
            if (s_w[m] > 0.f) {
                const float4 v = *(const float4*)&att[(((size_t)b * Hn + h) * Ln + s_idx[m]) * Ln + l];
                acc.x += v.x; acc.y += v.y; acc.z += v.z; acc.w += v.w;
            }
        }
        const unsigned u0 = (unsigned)f2bf(acc.x * s_inv) | ((unsigned)f2bf(acc.y * s_inv) << 16);
        const unsigned u1 = (unsigned)f2bf(acc.z * s_inv) | ((unsigned)f2bf(acc.w * s_inv) << 16);
        uint2 uu; uu.x = u0; uu.y = u1;
        *(uint2*)&ea2[((size_t)id) * Ln + l] = uu;
    }
}

// ---------------------------------------------------------------------------
// K3a: UNIQUE pair scores (i<j only — ht_att is (i,j)-symmetric).
// xb[b][u][l] (bf16), u in [0,861), and per-chunk partials Spart[b][chunk][u].
// grid = (CHUNKS, 2 halves, B), 256 threads
// ---------------------------------------------------------------------------
__global__ __launch_bounds__(256) void k_pairs(
    const unsigned short* __restrict__ ea2, unsigned short* __restrict__ xb,
    float* __restrict__ Spart)
{
    __shared__ unsigned sm[Hn * NEn * 17];   // [h*NE+e][16 uints + 1 pad]
    const int c    = blockIdx.x;
    const int half = blockIdx.y;
    const int b    = blockIdx.z;
    const int t    = threadIdx.x;

    const unsigned* eg = (const unsigned*)ea2 + ((size_t)b * Hn * NEn) * (Ln / 2) + c * (CL / 2);
    for (int id = t; id < Hn * NEn * 16; id += 256) {
        const int r = id >> 4, u = id & 15;
        sm[r * 17 + u] = eg[(size_t)r * (Ln / 2) + u];
    }
    __syncthreads();

    const int l2 = t & 15;       // uint index within chunk (2 l's each)
    const int pm = t >> 4;       // 0..15
    const int rend = (half + 1) * UHALF < UPn ? (half + 1) * UHALF : UPn;
    unsigned* xbu = (unsigned*)xb;
    for (int rk = half * UHALF + pm; rk < rend; rk += 16) {
        int i, j; u2ij(rk, i, j);
        float a0 = 0.f, a1 = 0.f;
        #pragma unroll
        for (int h = 0; h < Hn; ++h) {
            const unsigned ui = sm[(h * NEn + i) * 17 + l2];
            const unsigned uj = sm[(h * NEn + j) * 17 + l2];
            const float xi0 = __uint_as_float(ui << 16);
            const float xi1 = __uint_as_float(ui & 0xffff0000u);
            const float xj0 = __uint_as_float(uj << 16);
            const float xj1 = __uint_as_float(uj & 0xffff0000u);
            a0 = fmaf(xi0, xj0, a0);
            a1 = fmaf(xi1, xj1, a1);
        }
        xbu[((size_t)b * UPn + rk) * (Ln / 2) + c * (CL / 2) + l2] =
            (unsigned)f2bf(a0) | ((unsigned)f2bf(a1) << 16);
        float part = a0 + a1;
        part += __shfl_down(part, 8, 16);
        part += __shfl_down(part, 4, 16);
        part += __shfl_down(part, 2, 16);
        part += __shfl_down(part, 1, 16);
        if (l2 == 0)
            Spart[((size_t)b * CHUNKS + c) * UPn + rk] = part;
    }
}

// ---------------------------------------------------------------------------
// K4: bf16 MFMA GEMM over the 861 UNIQUE rows, double-buffered LDS, one
// barrier per K-iter.  Epilogue writes each row to BOTH output rows
// rank(i,j)=41i+j-1 and rank(j,i)=41j+i with the shared normalizer.
// 128x128 tile, BK=32, 4 waves (2x2), wave 64x64 via 4x4 16x16x32 MFMA.
// grid = (7, 6, 4) = 168 blocks — fully co-resident on 256 CUs.
// ---------------------------------------------------------------------------
__global__ __launch_bounds__(256) void k_gemm_mfma(
    const unsigned short* __restrict__ xb, const unsigned short* __restrict__ soT,
    const float* __restrict__ Spart, float* __restrict__ out2)
{
    __shared__ __align__(16) unsigned short As[2][128 * LDSW];
    __shared__ __align__(16) unsigned short Bs[2][128 * LDSW];
    __shared__ float s_scale[128];

    const int row0 = blockIdx.x * 128;
    const int col0 = blockIdx.y * 128;
    const int b    = blockIdx.z;
    const int t    = threadIdx.x;
    const int lane = t & 63;
    const int wave = t >> 6;
    const int wm = wave & 1, wn = wave >> 1;

    // fused k_sreduce: per-row normalizer (visible to epilogue via loop barriers)
    if (t < 128) {
        const int u = min(row0 + t, UPn - 1);
        float s = 0.f;
        #pragma unroll
        for (int cix = 0; cix < CHUNKS; ++cix)
            s += Spart[((size_t)b * CHUNKS + cix) * UPn + u];
        s_scale[t] = 1.0f / (s + (float)Hn * EPSn);
    }

    f32x4 acc[4][4];
    #pragma unroll
    for (int i2 = 0; i2 < 4; ++i2)
        #pragma unroll
        for (int j2 = 0; j2 < 4; ++j2)
            acc[i2][j2] = (f32x4){0.f, 0.f, 0.f, 0.f};

    // staging: thread t loads 16B of rows (t>>2) and (t>>2)+64 for both A and B
    const int sr = t >> 2;            // 0..63
    const int sc = (t & 3) * 8;       // element offset 0/8/16/24
    const int arow0 = min(row0 + sr,      UPn - 1);   // clamp tail rows (reads only)
    const int arow1 = min(row0 + sr + 64, UPn - 1);
    const size_t abase0 = ((size_t)b * UPn + arow0) * Ln + sc;
    const size_t abase1 = ((size_t)b * UPn + arow1) * Ln + sc;
    const size_t bbase0 = ((size_t)b * Dn + col0 + sr) * Ln + sc;
    const size_t bbase1 = ((size_t)b * Dn + col0 + sr + 64) * Ln + sc;

    const int fr = lane & 15;             // fragment row (m or n)
    const int fo = (lane >> 4) * 8;       // fragment k offset

    // prologue: tile 0 -> regs -> LDS buf 0
    bf16x8 a0 = *(const bf16x8*)(xb  + abase0);
    bf16x8 a1 = *(const bf16x8*)(xb  + abase1);
    bf16x8 b0 = *(const bf16x8*)(soT + bbase0);
    bf16x8 b1 = *(const bf16x8*)(soT + bbase1);
    *(bf16x8*)&As[0][sr * LDSW + sc]        = a0;
    *(bf16x8*)&As[0][(sr + 64) * LDSW + sc] = a1;
    *(bf16x8*)&Bs[0][sr * LDSW + sc]        = b0;
    *(bf16x8*)&Bs[0][(sr + 64) * LDSW + sc] = b1;
    __syncthreads();

    for (int k0 = 0; k0 < 32; ++k0) {
        const int cur = k0 & 1;
        // prefetch next tile into registers (hidden behind MFMA)
        if (k0 < 31) {
            const int kn = (k0 + 1) * 32;
            a0 = *(const bf16x8*)(xb  + abase0 + kn);
            a1 = *(const bf16x8*)(xb  + abase1 + kn);
            b0 = *(const bf16x8*)(soT + bbase0 + kn);
            b1 = *(const bf16x8*)(soT + bbase1 + kn);
        }

        bf16x8 af[4], bfr[4];
        #pragma unroll
        for (int mt = 0; mt < 4; ++mt)
            af[mt] = *(const bf16x8*)&As[cur][(wm * 64 + mt * 16 + fr) * LDSW + fo];
        #pragma unroll
        for (int nt = 0; nt < 4; ++nt)
            bfr[nt] = *(const bf16x8*)&Bs[cur][(wn * 64 + nt * 16 + fr) * LDSW + fo];
        #pragma unroll
        for (int mt = 0; mt < 4; ++mt)
            #pragma unroll
            for (int nt = 0; nt < 4; ++nt)
                acc[mt][nt] = __builtin_amdgcn_mfma_f32_16x16x32_bf16(
                    af[mt], bfr[nt], acc[mt][nt], 0, 0, 0);

        if (k0 < 31) {
            const int nxt = cur ^ 1;
            *(bf16x8*)&As[nxt][sr * LDSW + sc]        = a0;
            *(bf16x8*)&As[nxt][(sr + 64) * LDSW + sc] = a1;
            *(bf16x8*)&Bs[nxt][sr * LDSW + sc]        = b0;
            *(bf16x8*)&Bs[nxt][(sr + 64) * LDSW + sc] = b1;
            __syncthreads();
        }
    }

    const int ccol  = lane & 15;
    const int crow4 = (lane >> 4) * 4;
    #pragma unroll
    for (int mt = 0; mt < 4; ++mt) {
        #pragma unroll
        for (int rg = 0; rg < 4; ++rg) {
            const int ml = wm * 64 + mt * 16 + crow4 + rg;
            const int u  = row0 + ml;
            if (u < UPn) {
                int i, j; u2ij(u, i, j);
                const int r1 = i * (NEn - 1) + j - 1;   // rank(i,j), j>i
                const int r2 = j * (NEn - 1) + i;       // rank(j,i), i<j
                const float sc2 = s_scale[ml];
                float* dst1 = out2 + ((size_t)b * Pn + r1) * Dn + col0 + wn * 64 + ccol;
                float* dst2 = out2 + ((size_t)b * Pn + r2) * Dn + col0 + wn * 64 + ccol;
                #pragma unroll
                for (int nt = 0; nt < 4; ++nt) {
                    const float val = acc[mt][nt][rg] * sc2;
                    dst1[nt * 16] = val;
                    dst2[nt * 16] = val;
                }
            }
        }
    }
}

extern "C" void kernel_launch(void* const* d_in, const int* in_sizes, int n_in,
                              void* d_out, int out_size, void* d_ws, size_t ws_size,
                              hipStream_t stream)
{
    const float* so   = (const float*)d_in[0];   // (B, L, D)
    const float* att  = (const float*)d_in[1];   // (B, H, L, L)
    const float* mask = (const float*)d_in[2];   // (B, NE, M)
    const int*   mpos = (const int*)d_in[3];     // (B, NE, M)
    float* out = (float*)d_out;
    float* out_ee = out;                                  // B*NE*D
    float* out_ht = out + (size_t)Bn * NEn * Dn;          // B*P*D

    char* w = (char*)d_ws;
    unsigned short* ea2 = (unsigned short*)w; w += (size_t)Bn * Hn * NEn * Ln * 2;  // 4.13 MB
    unsigned short* xb  = (unsigned short*)w; w += (size_t)Bn * UPn * Ln * 2;       // 7.05 MB
    unsigned short* soT = (unsigned short*)w; w += (size_t)Bn * Dn * Ln * 2;        // 6.29 MB
    float* Spart = (float*)w;                                                       // 441 KB

    hipLaunchKernelGGL(k_prep, dim3(SOT_BLKS + EA_BLKS), dim3(256), 0, stream,
                       so, att, mask, mpos, soT, ea2);
    hipLaunchKernelGGL(k_pairs, dim3(CHUNKS, 2, Bn), dim3(256), 0, stream,
                       ea2, xb, Spart);
    hipLaunchKernelGGL(k_gemm_mfma, dim3((UPn + 127) / 128, Dn / 128, Bn), dim3(256), 0, stream,
                       xb, soT, Spart, out_ht);
    // entity_embed last: output-0 region written by exactly one kernel, at the end
    hipLaunchKernelGGL(k_entity_embed, dim3(Bn * NEn), dim3(256), 0, stream,
                       so, mask, mpos, out_ee);
}